// Round 12
// baseline (435.554 us; speedup 1.0000x reference)
//
#include <hip/hip_runtime.h>
#include <math.h>

// Problem geometry (fixed by setup_inputs): x = (8, 4096, 4, 3, 128) fp32
// Viewed as (B=8, M=16384, 3, D=128). k = M/10 = 1638 (1-indexed) -> rank 1637.
#define BATCH 8
#define M     16384
#define D     128
#define RANK0 1637u

// clang-native 4-float vector: required by __builtin_nontemporal_{load,store}
// (HIP's float4 is a struct wrapper the builtin rejects). Same 16B size,
// alignment, and layout; supports .x/.y/.z/.w swizzles.
typedef float f32x4 __attribute__((ext_vector_type(4)));

// ---------------- P1: norms + transpose to column-major ----------------
// grid = BATCH * (M/TM) blocks, 256 threads.
// Reads x coalesced (f32x4 over d) with NORMAL loads (we want x resident in
// L3 for P3's re-read), computes norm with the reference's exact fp32
// arithmetic (no contraction), LDS-transposes to [d][m], writes norms
// column-major with NON-TEMPORAL stores (single-use scratch, keep L3 for x):
// nrm[(b*D + d)*M + m], contiguous in m.
#define TM      64
#define LSTRIDE (TM + 4)   // 68: pad keeps 16B alignment, breaks pow2 stride

__global__ __launch_bounds__(256) void norms_transpose_k(
    const float* __restrict__ x, float* __restrict__ nrm) {
#pragma clang fp contract(off)
    __shared__ float tile[D * LSTRIDE];   // ~34 KB -> 4 blocks/CU
    const int blk = blockIdx.x;
    const int b  = blk >> 8;             // M/TM = 256 tiles per batch
    const int mt = blk & 255;
    const int m0 = mt * TM;
    const int tid = threadIdx.x;

    // compute phase: thread -> (4 consecutive d, one m per iteration)
    const int d4  = tid & 31;            // d group: d = 4*d4 + j
    const int mib = tid >> 5;            // 0..7
    const float* xb = x + ((size_t)(b * M + m0)) * (3 * D);
    for (int mi = mib; mi < TM; mi += 8) {
        const float* xm = xb + (size_t)mi * (3 * D) + d4 * 4;
        f32x4 a0 = *reinterpret_cast<const f32x4*>(xm);
        f32x4 a1 = *reinterpret_cast<const f32x4*>(xm + D);
        f32x4 a2 = *reinterpret_cast<const f32x4*>(xm + 2 * D);
        tile[(d4 * 4 + 0) * LSTRIDE + mi] =
            sqrtf(((a0.x * a0.x) + (a1.x * a1.x)) + (a2.x * a2.x));
        tile[(d4 * 4 + 1) * LSTRIDE + mi] =
            sqrtf(((a0.y * a0.y) + (a1.y * a1.y)) + (a2.y * a2.y));
        tile[(d4 * 4 + 2) * LSTRIDE + mi] =
            sqrtf(((a0.z * a0.z) + (a1.z * a1.z)) + (a2.z * a2.z));
        tile[(d4 * 4 + 3) * LSTRIDE + mi] =
            sqrtf(((a0.w * a0.w) + (a1.w * a1.w)) + (a2.w * a2.w));
    }
    __syncthreads();

    // write phase: row d -> 64 contiguous floats of m (16 f32x4 per row)
    const int f4 = tid & 15;
    for (int r = tid >> 4; r < D; r += 16) {
        f32x4 v = *reinterpret_cast<const f32x4*>(&tile[r * LSTRIDE + f4 * 4]);
        __builtin_nontemporal_store(
            v, reinterpret_cast<f32x4*>(
                   &nrm[((size_t)(b * D + r)) * M + m0 + f4 * 4]));
    }
}

// ---------------- P2: exact radix-select of rank-1637 per column ----------------
// One block (256 threads) per column (b*D+d). Norms are non-negative, so the
// uint32 bit pattern is order-isomorphic. 3 rounds: bits[31:21],[20:10],[9:0].
// All __syncthreads() are wave-uniform (no divergent barriers).
__global__ __launch_bounds__(256) void select_kth_k(
    const float* __restrict__ nrm, float* __restrict__ kx) {
    __shared__ float    data[M];       // 64 KB
    __shared__ unsigned hist[2048];    // 8 KB
    __shared__ unsigned psum[256];
    __shared__ unsigned sel[2];
    const int col = blockIdx.x;
    const int tid = threadIdx.x;

    // nrm is single-use scratch: non-temporal loads keep L3 for x.
    const f32x4* src = reinterpret_cast<const f32x4*>(nrm + (size_t)col * M);
    f32x4* dst = reinterpret_cast<f32x4*>(data);
    for (int i = tid; i < M / 4; i += 256)
        dst[i] = __builtin_nontemporal_load(&src[i]);
    __syncthreads();

    unsigned prefix = 0u, pmask = 0u;
    unsigned rank = RANK0;
    const int shifts[3] = {21, 10, 0};
    const int nbins[3]  = {2048, 2048, 1024};

    for (int r = 0; r < 3; ++r) {
        const int s  = shifts[r];
        const int nb = nbins[r];
        for (int i = tid; i < nb; i += 256) hist[i] = 0u;
        __syncthreads();
        for (int i = tid; i < M; i += 256) {
            unsigned u = __float_as_uint(data[i]);
            if ((u & pmask) == prefix)
                atomicAdd(&hist[(u >> s) & (unsigned)(nb - 1)], 1u);
        }
        __syncthreads();
        // chunked prefix over bins: cw bins per thread
        const int cw   = nb >> 8;
        const int base = tid * cw;
        unsigned mysum = 0u;
        for (int j = 0; j < cw; ++j) mysum += hist[base + j];
        psum[tid] = mysum;
        __syncthreads();
        unsigned pre = 0u;
        for (int j = 0; j < tid; ++j) pre += psum[j];  // broadcast LDS reads
        if (rank >= pre && rank < pre + mysum) {       // exactly one winner
            unsigned rr = rank - pre;
            for (int j = 0; j < cw; ++j) {
                unsigned c = hist[base + j];
                if (rr < c) { sel[0] = (unsigned)(base + j); sel[1] = rr; break; }
                rr -= c;
            }
        }
        __syncthreads();
        prefix |= sel[0] << s;
        pmask  |= (unsigned)(nb - 1) << s;
        rank = sel[1];
        __syncthreads();
    }
    if (tid == 0) kx[col] = __uint_as_float(prefix);
}

// ---------------- P3: apply threshold, write output ----------------
// Thread handles one (b,m, 4 d's): 3 f32x4 loads (L3-resident from P1 if the
// nt hints preserved x), bit-exact norm recompute, strict > compare (matches
// reference tie semantics), 3 NON-TEMPORAL f32x4 stores (out never re-read).
__global__ __launch_bounds__(256) void apply_mask_k(
    const float* __restrict__ x, const float* __restrict__ kx,
    float* __restrict__ out) {
#pragma clang fp contract(off)
    const size_t idx = (size_t)blockIdx.x * 256 + threadIdx.x;
    const int    d4  = (int)(idx & 31);
    const size_t bm  = idx >> 5;          // b*M + m, 0..131071
    const int    b   = (int)(bm >> 14);   // M = 2^14
    const f32x4* x4 = reinterpret_cast<const f32x4*>(x);
    f32x4*       o4 = reinterpret_cast<f32x4*>(out);
    const size_t base = bm * 96 + (size_t)d4;   // row = 3*128 floats = 96 f32x4
    f32x4 a0 = x4[base];
    f32x4 a1 = x4[base + 32];
    f32x4 a2 = x4[base + 64];
    f32x4 kv = reinterpret_cast<const f32x4*>(kx)[(b << 5) + d4];
    f32x4 r0, r1, r2;
    {
        float n = sqrtf(((a0.x * a0.x) + (a1.x * a1.x)) + (a2.x * a2.x));
        bool keep = n > kv.x;
        r0.x = keep ? a0.x : 0.0f; r1.x = keep ? a1.x : 0.0f; r2.x = keep ? a2.x : 0.0f;
    }
    {
        float n = sqrtf(((a0.y * a0.y) + (a1.y * a1.y)) + (a2.y * a2.y));
        bool keep = n > kv.y;
        r0.y = keep ? a0.y : 0.0f; r1.y = keep ? a1.y : 0.0f; r2.y = keep ? a2.y : 0.0f;
    }
    {
        float n = sqrtf(((a0.z * a0.z) + (a1.z * a1.z)) + (a2.z * a2.z));
        bool keep = n > kv.z;
        r0.z = keep ? a0.z : 0.0f; r1.z = keep ? a1.z : 0.0f; r2.z = keep ? a2.z : 0.0f;
    }
    {
        float n = sqrtf(((a0.w * a0.w) + (a1.w * a1.w)) + (a2.w * a2.w));
        bool keep = n > kv.w;
        r0.w = keep ? a0.w : 0.0f; r1.w = keep ? a1.w : 0.0f; r2.w = keep ? a2.w : 0.0f;
    }
    __builtin_nontemporal_store(r0, &o4[base]);
    __builtin_nontemporal_store(r1, &o4[base + 32]);
    __builtin_nontemporal_store(r2, &o4[base + 64]);
}

extern "C" void kernel_launch(void* const* d_in, const int* in_sizes, int n_in,
                              void* d_out, int out_size, void* d_ws, size_t ws_size,
                              hipStream_t stream) {
    (void)in_sizes; (void)n_in; (void)out_size; (void)ws_size;
    const float* x  = (const float*)d_in[0];
    float* out = (float*)d_out;
    // Use d_out as norm scratch (16.7M floats = 67 MB << 201 MB output buffer);
    // P3 fully overwrites every element of d_out afterwards, so the harness's
    // 0xAA poison never leaks into the validated output.
    float* nrm = out;
    float* kx  = (float*)d_ws;   // 1024 floats = 4 KB, well under ws_size

    // P1: 8 batches * 256 m-tiles = 2048 blocks
    hipLaunchKernelGGL(norms_transpose_k, dim3(BATCH * (M / TM)), dim3(256), 0,
                       stream, x, nrm);
    // P2: one block per (b,d) column
    hipLaunchKernelGGL(select_kth_k, dim3(BATCH * D), dim3(256), 0,
                       stream, nrm, kx);
    // P3: B*M*(D/4) threads = 4,194,304 -> 16384 blocks
    hipLaunchKernelGGL(apply_mask_k, dim3((BATCH * M * (D / 4)) / 256), dim3(256),
                       0, stream, x, kx, out);
}